// Round 7
// baseline (189.293 us; speedup 1.0000x reference)
//
#include <hip/hip_runtime.h>

// Morphological dilation2d on MI355X (gfx950).
// out[b,o,h,w] = max_{c,i,j} ( x_zpad[b,c,h+i-2,w+j-2] + weight[o,c,i,j] )
// B=4, C=4, O=4, H=W=1024, K=5, PAD=2, fp32.
//
// Round-7: vertical register blocking. Each thread owns 4 output rows x 4 cols
// (tile 32x128). One 12-float window read at input row r feeds ALL overlapping
// output rows (i = r - out_row): 8 window reads per c serve 16 px -> 0.5
// ds_read_b128-triples/px vs 1.25 before. Window marshalling and bank
// conflicts drop 2.5x; core add/max per px unchanged (irreducible).
// x is staged per-c (36x136 = 19.6 KB LDS) with two barriers per c.
// Weights: R6's device-global duplicated pairs (proven correct, neutral cost).
// No inline asm (R1/R4: asm pays a mov tax; compiler selection is optimal).

constexpr int Himg = 1024, Wimg = 1024, Cin = 4, Cout = 4, Kn = 5;
constexpr int TH = 32, TW = 128;    // output tile per 256-thread block
constexpr int RPT = 4;              // output rows per thread
constexpr int LRows = TH + 4;       // 36 staged input rows per c-slice
constexpr int LC = TW + 8;          // 136 cols (halo -4..+3 keeps b128 reads aligned)
constexpr int LC4 = LC / 4;         // 34 float4 chunks per row
constexpr int NW = Cout * Cin * Kn * Kn;  // 400 weights

typedef float v2f __attribute__((ext_vector_type(2)));

// Device-global scratch: duplicated weight pairs, [c][i][o][j] = {w, w}. 3.2 KB.
__device__ __align__(16) v2f wdup[Cin * Kn * Cout * Kn];

// weight [o][c][i][j] -> wdup[c][i][o][j] = {w, w}
__global__ void reorg_w(const float* __restrict__ w) {
  int idx = threadIdx.x;
  if (idx < NW) {
    int o  = idx / (Cin * Kn * Kn);
    int r  = idx % (Cin * Kn * Kn);
    int c  = r / (Kn * Kn);
    int r2 = r % (Kn * Kn);
    int i  = r2 / Kn, j = r2 % Kn;
    float v = w[idx];
    v2f p; p.x = v; p.y = v;
    wdup[((c * Kn + i) * Cout + o) * Kn + j] = p;
  }
}

// 5-input max folded so LLVM forms v_max3_f32.
__device__ __forceinline__ float max5(float a, float b, float c, float d, float e) {
  return fmaxf(fmaxf(a, b), fmaxf(c, fmaxf(d, e)));
}

__global__ __launch_bounds__(256, 4) void morph(const float* __restrict__ x,
                                                float* __restrict__ out) {
  __shared__ __align__(16) float xs[LRows][LC];   // one c-slice at a time
  const int tid = threadIdx.x;
  const int tile_w0 = blockIdx.x * TW;
  const int tile_r0 = blockIdx.y * TH;
  const int b = blockIdx.z;

  const int tx = tid & 31;   // 32 thread-cols x 4 px
  const int ty = tid >> 5;   // 8 row-groups x 4 rows

  float acc[Cout][RPT][4];
#pragma unroll
  for (int o = 0; o < Cout; ++o)
#pragma unroll
    for (int k = 0; k < RPT; ++k)
#pragma unroll
      for (int p = 0; p < 4; ++p) acc[o][k][p] = -3.4e38f;

// Accumulate one (input-row, out-row K, channel pair set) block:
// 10 v_pk_add_f32 + 4 x max5 tree folded into acc[O][K][*].
#define ACC_KO(K, O, WDP)                                                                 \
  do {                                                                                    \
    v2f p01[5], p23[5];                                                                   \
    _Pragma("unroll") for (int j = 0; j < 5; ++j) {                                       \
      v2f wb = (WDP)[(O) * Kn + j];                                                       \
      p01[j] = a2[j] + wb;                                                                \
      p23[j] = b2[j] + wb;                                                                \
    }                                                                                     \
    acc[O][K][0] = fmaxf(acc[O][K][0], max5(p01[0].x, p01[1].x, p01[2].x, p01[3].x, p01[4].x)); \
    acc[O][K][1] = fmaxf(acc[O][K][1], max5(p01[0].y, p01[1].y, p01[2].y, p01[3].y, p01[4].y)); \
    acc[O][K][2] = fmaxf(acc[O][K][2], max5(p23[0].x, p23[1].x, p23[2].x, p23[3].x, p23[4].x)); \
    acc[O][K][3] = fmaxf(acc[O][K][3], max5(p23[0].y, p23[1].y, p23[2].y, p23[3].y, p23[4].y)); \
  } while (0)

#pragma unroll 1
  for (int c = 0; c < Cin; ++c) {
    __syncthreads();  // previous c-slice fully consumed before overwrite

    // ---- stage c-slice (+halo, zero pad) into LDS, float4 coalesced ----
    for (int idx = tid; idx < LRows * LC4; idx += 256) {
      const int row = idx / LC4;
      const int ch  = idx - row * LC4;
      const int gr  = tile_r0 - 2 + row;
      const int gc  = tile_w0 - 4 + ch * 4;
      float4 v = make_float4(0.f, 0.f, 0.f, 0.f);
      if ((unsigned)gr < (unsigned)Himg) {
        const float* src = x + ((size_t)(b * Cin + c) * Himg + gr) * Wimg;
        if (gc >= 0 && gc <= Wimg - 4) {
          v = *(const float4*)(src + gc);
        } else {
          if ((unsigned)(gc + 0) < (unsigned)Wimg) v.x = src[gc + 0];
          if ((unsigned)(gc + 1) < (unsigned)Wimg) v.y = src[gc + 1];
          if ((unsigned)(gc + 2) < (unsigned)Wimg) v.z = src[gc + 2];
          if ((unsigned)(gc + 3) < (unsigned)Wimg) v.w = src[gc + 3];
        }
      }
      *(float4*)&xs[row][ch * 4] = v;
    }
    __syncthreads();

    // ---- 8 input-row windows serve 4 output rows (16 px) ----
#pragma unroll
    for (int dr = 0; dr < RPT + 4; ++dr) {   // local input rows ty*4 .. ty*4+7
      const float* rowp = &xs[ty * RPT + dr][tx * 4];
      float4 q0 = *(const float4*)(rowp);
      float4 q1 = *(const float4*)(rowp + 4);
      float4 q2 = *(const float4*)(rowp + 8);
      float win[12] = {q0.x, q0.y, q0.z, q0.w, q1.x, q1.y, q1.z, q1.w,
                       q2.x, q2.y, q2.z, q2.w};

      // window pairs, shared across all out-rows and output channels
      v2f a2[5], b2[5];
#pragma unroll
      for (int j = 0; j < 5; ++j) {
        a2[j].x = win[2 + j]; a2[j].y = win[3 + j];
        b2[j].x = win[4 + j]; b2[j].y = win[5 + j];
      }

#pragma unroll
      for (int k = 0; k < RPT; ++k) {
        const int i = dr - k;                 // kernel row; compile-time after unroll
        if (i >= 0 && i < Kn) {
          const v2f* wdp = wdup + (c * Kn + i) * Cout * Kn;
          ACC_KO(k, 0, wdp);
          ACC_KO(k, 1, wdp);
          ACC_KO(k, 2, wdp);
          ACC_KO(k, 3, wdp);
        }
      }
    }
  }
#undef ACC_KO

  // ---- epilogue: float4 stores, coalesced ----
  const int gc0 = tile_w0 + tx * 4;
#pragma unroll
  for (int o = 0; o < Cout; ++o)
#pragma unroll
    for (int k = 0; k < RPT; ++k) {
      const int r = tile_r0 + ty * RPT + k;
      float4 res = make_float4(acc[o][k][0], acc[o][k][1], acc[o][k][2], acc[o][k][3]);
      *(float4*)&out[((size_t)(b * Cout + o) * Himg + r) * Wimg + gc0] = res;
    }
}

extern "C" void kernel_launch(void* const* d_in, const int* in_sizes, int n_in,
                              void* d_out, int out_size, void* d_ws, size_t ws_size,
                              hipStream_t stream) {
  const float* x = (const float*)d_in[0];
  const float* w = (const float*)d_in[1];
  float* out = (float*)d_out;

  reorg_w<<<dim3(1), dim3(512), 0, stream>>>(w);

  dim3 grid(Wimg / TW, Himg / TH, 4);  // (8, 32, 4) = 1024 blocks
  morph<<<grid, dim3(256), 0, stream>>>(x, out);
}

// Round 8
// 158.836 us; speedup vs baseline: 1.1918x; 1.1918x over previous
//
#include <hip/hip_runtime.h>

// Morphological dilation2d on MI355X (gfx950).
// out[b,o,h,w] = max_{c,i,j} ( x_zpad[b,c,h+i-2,w+j-2] + weight[o,c,i,j] )
// B=4, C=4, O=4, H=W=1024, K=5, PAD=2, fp32.
//
// Round-8: vertical register blocking at a NO-SPILL budget. R7 (RPT=4) proved
// the mechanism (bank conflicts 5.24M->2.1M, = predicted) but spilled its
// 64-reg accumulator (WRITE_SIZE 65->139 MB). RPT=2: acc = 32 VGPRs, est
// total ~90 -> ~5 waves/SIMD, no spill. Each thread: 2 output rows x 4 cols
// (tile 16x128). Per c, 6 window reads serve 8 px (0.75 reads/px vs R0's
// 1.25): ds_read issue, lgkm stalls, pair marshalling and conflicts all
// -40%. Core add/max per px unchanged (irreducible). x staged per-c
// (20x136 = 10.9 KB LDS) to keep occupancy; weights = R6's device-global
// duplicated SGPR pairs (proven neutral). No inline asm; no launch_bounds
// min-waves (R7 interaction).

constexpr int Himg = 1024, Wimg = 1024, Cin = 4, Cout = 4, Kn = 5;
constexpr int TH = 16, TW = 128;    // output tile per 256-thread block
constexpr int RPT = 2;              // output rows per thread
constexpr int LRows = TH + 4;       // 20 staged input rows per c-slice
constexpr int LC = TW + 8;          // 136 cols (halo -4..+3 keeps b128 reads aligned)
constexpr int LC4 = LC / 4;         // 34 float4 chunks per row
constexpr int NW = Cout * Cin * Kn * Kn;  // 400 weights

typedef float v2f __attribute__((ext_vector_type(2)));

// Device-global scratch: duplicated weight pairs, [c][i][o][j] = {w, w}. 3.2 KB.
__device__ __align__(16) v2f wdup[Cin * Kn * Cout * Kn];

// weight [o][c][i][j] -> wdup[c][i][o][j] = {w, w}
__global__ void reorg_w(const float* __restrict__ w) {
  int idx = threadIdx.x;
  if (idx < NW) {
    int o  = idx / (Cin * Kn * Kn);
    int r  = idx % (Cin * Kn * Kn);
    int c  = r / (Kn * Kn);
    int r2 = r % (Kn * Kn);
    int i  = r2 / Kn, j = r2 % Kn;
    float v = w[idx];
    v2f p; p.x = v; p.y = v;
    wdup[((c * Kn + i) * Cout + o) * Kn + j] = p;
  }
}

// 5-input max folded so LLVM forms v_max3_f32.
__device__ __forceinline__ float max5(float a, float b, float c, float d, float e) {
  return fmaxf(fmaxf(a, b), fmaxf(c, fmaxf(d, e)));
}

__global__ __launch_bounds__(256) void morph(const float* __restrict__ x,
                                             float* __restrict__ out) {
  __shared__ __align__(16) float xs[LRows][LC];   // one c-slice at a time (10.9 KB)
  const int tid = threadIdx.x;
  const int tile_w0 = blockIdx.x * TW;
  const int tile_r0 = blockIdx.y * TH;
  const int b = blockIdx.z;

  const int tx = tid & 31;   // 32 thread-cols x 4 px
  const int ty = tid >> 5;   // 8 row-groups x 2 rows

  float acc[Cout][RPT][4];
#pragma unroll
  for (int o = 0; o < Cout; ++o)
#pragma unroll
    for (int k = 0; k < RPT; ++k)
#pragma unroll
      for (int p = 0; p < 4; ++p) acc[o][k][p] = -3.4e38f;

// One (out-row K, channel O) contribution from the current window:
// 10 v_pk_add_f32 + 4 x max5 tree folded into acc[O][K][*].
#define ACC_KO(K, O, WDP)                                                                 \
  do {                                                                                    \
    v2f p01[5], p23[5];                                                                   \
    _Pragma("unroll") for (int j = 0; j < 5; ++j) {                                       \
      v2f wb = (WDP)[(O) * Kn + j];                                                       \
      p01[j] = a2[j] + wb;                                                                \
      p23[j] = b2[j] + wb;                                                                \
    }                                                                                     \
    acc[O][K][0] = fmaxf(acc[O][K][0], max5(p01[0].x, p01[1].x, p01[2].x, p01[3].x, p01[4].x)); \
    acc[O][K][1] = fmaxf(acc[O][K][1], max5(p01[0].y, p01[1].y, p01[2].y, p01[3].y, p01[4].y)); \
    acc[O][K][2] = fmaxf(acc[O][K][2], max5(p23[0].x, p23[1].x, p23[2].x, p23[3].x, p23[4].x)); \
    acc[O][K][3] = fmaxf(acc[O][K][3], max5(p23[0].y, p23[1].y, p23[2].y, p23[3].y, p23[4].y)); \
  } while (0)

#pragma unroll 1
  for (int c = 0; c < Cin; ++c) {
    __syncthreads();  // previous c-slice fully consumed before overwrite

    // ---- stage c-slice (+halo, zero pad) into LDS, float4 coalesced ----
    for (int idx = tid; idx < LRows * LC4; idx += 256) {
      const int row = idx / LC4;
      const int ch  = idx - row * LC4;
      const int gr  = tile_r0 - 2 + row;
      const int gc  = tile_w0 - 4 + ch * 4;
      float4 v = make_float4(0.f, 0.f, 0.f, 0.f);
      if ((unsigned)gr < (unsigned)Himg) {
        const float* src = x + ((size_t)(b * Cin + c) * Himg + gr) * Wimg;
        if (gc >= 0 && gc <= Wimg - 4) {
          v = *(const float4*)(src + gc);
        } else {
          if ((unsigned)(gc + 0) < (unsigned)Wimg) v.x = src[gc + 0];
          if ((unsigned)(gc + 1) < (unsigned)Wimg) v.y = src[gc + 1];
          if ((unsigned)(gc + 2) < (unsigned)Wimg) v.z = src[gc + 2];
          if ((unsigned)(gc + 3) < (unsigned)Wimg) v.w = src[gc + 3];
        }
      }
      *(float4*)&xs[row][ch * 4] = v;
    }
    __syncthreads();

    // ---- 6 input-row windows serve 2 output rows (8 px) ----
#pragma unroll
    for (int dr = 0; dr < RPT + 4; ++dr) {   // local input rows ty*2 .. ty*2+5
      const float* rowp = &xs[ty * RPT + dr][tx * 4];
      float4 q0 = *(const float4*)(rowp);
      float4 q1 = *(const float4*)(rowp + 4);
      float4 q2 = *(const float4*)(rowp + 8);
      float win[12] = {q0.x, q0.y, q0.z, q0.w, q1.x, q1.y, q1.z, q1.w,
                       q2.x, q2.y, q2.z, q2.w};

      // window pairs, shared across both out-rows and all output channels
      v2f a2[5], b2[5];
#pragma unroll
      for (int j = 0; j < 5; ++j) {
        a2[j].x = win[2 + j]; a2[j].y = win[3 + j];
        b2[j].x = win[4 + j]; b2[j].y = win[5 + j];
      }

#pragma unroll
      for (int k = 0; k < RPT; ++k) {
        const int i = dr - k;                 // kernel row; compile-time after unroll
        if (i >= 0 && i < Kn) {
          const v2f* wdp = wdup + (c * Kn + i) * Cout * Kn;
          ACC_KO(k, 0, wdp);
          ACC_KO(k, 1, wdp);
          ACC_KO(k, 2, wdp);
          ACC_KO(k, 3, wdp);
        }
      }
    }
  }
#undef ACC_KO

  // ---- epilogue: float4 stores, coalesced ----
  const int gc0 = tile_w0 + tx * 4;
#pragma unroll
  for (int o = 0; o < Cout; ++o)
#pragma unroll
    for (int k = 0; k < RPT; ++k) {
      const int r = tile_r0 + ty * RPT + k;
      float4 res = make_float4(acc[o][k][0], acc[o][k][1], acc[o][k][2], acc[o][k][3]);
      *(float4*)&out[((size_t)(b * Cout + o) * Himg + r) * Wimg + gc0] = res;
    }
}

extern "C" void kernel_launch(void* const* d_in, const int* in_sizes, int n_in,
                              void* d_out, int out_size, void* d_ws, size_t ws_size,
                              hipStream_t stream) {
  const float* x = (const float*)d_in[0];
  const float* w = (const float*)d_in[1];
  float* out = (float*)d_out;

  reorg_w<<<dim3(1), dim3(512), 0, stream>>>(w);

  dim3 grid(Wimg / TW, Himg / TH, 4);  // (8, 64, 4) = 2048 blocks
  morph<<<grid, dim3(256), 0, stream>>>(x, out);
}

// Round 10
// 153.291 us; speedup vs baseline: 1.2349x; 1.0362x over previous
//
#include <hip/hip_runtime.h>

// Morphological dilation2d on MI355X (gfx950).
// out[b,o,h,w] = max_{c,i,j} ( x_zpad[b,c,h+i-2,w+j-2] + weight[o,c,i,j] )
// B=4, C=4, O=4, H=W=1024, K=5, PAD=2, fp32.
//
// Round-10 == round-9 resubmit (bench infra failed twice; hypothesis untested).
// ILP batching of LDS reads. R0's codegen (VGPR=40) kept ds_reads just-in-time:
// 20 dependent load->wait->compute chains per wave. Here each c loads ALL 5
// row-windows (15 independent ds_read_b128) before computing the 5 i-blocks
// straight-line: one lgkm exposure per c instead of five.
// __launch_bounds__(256,4) grants 128 VGPRs so the allocator keeps ~60 window
// regs live (R7's spill needed >128; this needs ~110). Hot-loop arithmetic,
// LDS layout, staging and weight path are byte-identical to the 73.4us R6.
// Vertical blocking is dead (R5/R7/R8); no inline asm (R1/R4).

constexpr int Himg = 1024, Wimg = 1024, Cin = 4, Cout = 4, Kn = 5;
constexpr int TH = 8, TW = 128;     // output tile per 256-thread block
constexpr int LR = TH + 4;          // 12 LDS rows (halo +-2)
constexpr int LC = TW + 8;          // 136 LDS cols (halo -4..+3 for aligned b128 window reads)
constexpr int LC4 = LC / 4;         // 34 float4 chunks per row
constexpr int NW = Cout * Cin * Kn * Kn;  // 400 weights

typedef float v2f __attribute__((ext_vector_type(2)));

// Device-global scratch: duplicated weight pairs, [c][i][o][j] = {w, w}. 3.2 KB.
__device__ __align__(16) v2f wdup[Cin * Kn * Cout * Kn];

// weight [o][c][i][j] -> wdup[c][i][o][j] = {w, w}
__global__ void reorg_w(const float* __restrict__ w) {
  int idx = threadIdx.x;
  if (idx < NW) {
    int o  = idx / (Cin * Kn * Kn);
    int r  = idx % (Cin * Kn * Kn);
    int c  = r / (Kn * Kn);
    int r2 = r % (Kn * Kn);
    int i  = r2 / Kn, j = r2 % Kn;
    float v = w[idx];
    v2f p; p.x = v; p.y = v;
    wdup[((c * Kn + i) * Cout + o) * Kn + j] = p;
  }
}

// 5-input max folded so LLVM forms v_max3_f32: max3(a,b,max3(c,d,e)) shape.
__device__ __forceinline__ float max5(float a, float b, float c, float d, float e) {
  return fmaxf(fmaxf(a, b), fmaxf(c, fmaxf(d, e)));
}

__global__ __launch_bounds__(256, 4) void morph(const float* __restrict__ x,
                                                float* __restrict__ out) {
  __shared__ __align__(16) float xs[Cin][LR][LC];
  const int tid = threadIdx.x;
  const int tile_w0 = blockIdx.x * TW;
  const int tile_r0 = blockIdx.y * TH;
  const int b = blockIdx.z;

  // ---- stage x tile (+halo, zero pad) into LDS, float4 coalesced ----
  for (int idx = tid; idx < Cin * LR * LC4; idx += 256) {
    const int c   = idx / (LR * LC4);
    const int rem = idx - c * (LR * LC4);
    const int row = rem / LC4;
    const int ch  = rem - row * LC4;
    const int gr  = tile_r0 - 2 + row;
    const int gc  = tile_w0 - 4 + ch * 4;
    float4 v = make_float4(0.f, 0.f, 0.f, 0.f);
    if ((unsigned)gr < (unsigned)Himg) {
      const float* src = x + ((size_t)(b * Cin + c) * Himg + gr) * Wimg;
      if (gc >= 0 && gc <= Wimg - 4) {
        v = *(const float4*)(src + gc);
      } else {
        if ((unsigned)(gc + 0) < (unsigned)Wimg) v.x = src[gc + 0];
        if ((unsigned)(gc + 1) < (unsigned)Wimg) v.y = src[gc + 1];
        if ((unsigned)(gc + 2) < (unsigned)Wimg) v.z = src[gc + 2];
        if ((unsigned)(gc + 3) < (unsigned)Wimg) v.w = src[gc + 3];
      }
    }
    *(float4*)&xs[c][row][ch * 4] = v;
  }
  __syncthreads();

  const int tx = tid & 31;   // 32 thread-cols x 4 px
  const int ty = tid >> 5;   // 8 rows

  float acc[Cout][4];
#pragma unroll
  for (int o = 0; o < Cout; ++o)
#pragma unroll
    for (int p = 0; p < 4; ++p) acc[o][p] = -3.4e38f;

// Per output-channel O: 10 packed adds (v_pk_add_f32, SGPR-pair weight operand)
// + 4 x (max5 tree + acc fold).
#define ACC_O(O, WDP)                                                                     \
  do {                                                                                    \
    v2f p01[5], p23[5];                                                                   \
    _Pragma("unroll") for (int j = 0; j < 5; ++j) {                                       \
      v2f wb = (WDP)[(O) * Kn + j];                                                       \
      p01[j] = a2[j] + wb;                                                                \
      p23[j] = b2[j] + wb;                                                                \
    }                                                                                     \
    acc[O][0] = fmaxf(acc[O][0], max5(p01[0].x, p01[1].x, p01[2].x, p01[3].x, p01[4].x)); \
    acc[O][1] = fmaxf(acc[O][1], max5(p01[0].y, p01[1].y, p01[2].y, p01[3].y, p01[4].y)); \
    acc[O][2] = fmaxf(acc[O][2], max5(p23[0].x, p23[1].x, p23[2].x, p23[3].x, p23[4].x)); \
    acc[O][3] = fmaxf(acc[O][3], max5(p23[0].y, p23[1].y, p23[2].y, p23[3].y, p23[4].y)); \
  } while (0)

#pragma unroll 1
  for (int c = 0; c < Cin; ++c) {
    // ---- batch-load ALL 5 row-windows for this c: 15 independent
    //      ds_read_b128, one lgkm wait, then straight-line compute ----
    float4 qa[Kn][3];
#pragma unroll
    for (int dr = 0; dr < Kn; ++dr) {
      const float* rowp = &xs[c][ty + dr][tx * 4];
      qa[dr][0] = *(const float4*)(rowp);
      qa[dr][1] = *(const float4*)(rowp + 4);
      qa[dr][2] = *(const float4*)(rowp + 8);
    }

#pragma unroll
    for (int i = 0; i < Kn; ++i) {
      const float win[12] = {qa[i][0].x, qa[i][0].y, qa[i][0].z, qa[i][0].w,
                             qa[i][1].x, qa[i][1].y, qa[i][1].z, qa[i][1].w,
                             qa[i][2].x, qa[i][2].y, qa[i][2].z, qa[i][2].w};

      // window pairs, shared across the 4 output channels
      v2f a2[5], b2[5];
#pragma unroll
      for (int j = 0; j < 5; ++j) {
        a2[j].x = win[2 + j]; a2[j].y = win[3 + j];
        b2[j].x = win[4 + j]; b2[j].y = win[5 + j];
      }

      // wave-uniform duplicated pairs -> SGPR pairs feeding v_pk_add_f32
      const v2f* wdp = wdup + (c * Kn + i) * Cout * Kn;

      ACC_O(0, wdp);
      ACC_O(1, wdp);
      ACC_O(2, wdp);
      ACC_O(3, wdp);
    }
  }
#undef ACC_O

  // ---- epilogue: float4 stores, coalesced ----
  const int r = tile_r0 + ty;
  const int gc0 = tile_w0 + tx * 4;
#pragma unroll
  for (int o = 0; o < Cout; ++o) {
    float4 res = make_float4(acc[o][0], acc[o][1], acc[o][2], acc[o][3]);
    *(float4*)&out[((size_t)(b * Cout + o) * Himg + r) * Wimg + gc0] = res;
  }
}

extern "C" void kernel_launch(void* const* d_in, const int* in_sizes, int n_in,
                              void* d_out, int out_size, void* d_ws, size_t ws_size,
                              hipStream_t stream) {
  const float* x = (const float*)d_in[0];
  const float* w = (const float*)d_in[1];
  float* out = (float*)d_out;

  reorg_w<<<dim3(1), dim3(512), 0, stream>>>(w);

  dim3 grid(Wimg / TW, Himg / TH, 4);  // (8, 128, 4) = 4096 blocks
  morph<<<grid, dim3(256), 0, stream>>>(x, out);
}